// Round 16
// baseline (329.877 us; speedup 1.0000x reference)
//
#include <hip/hip_runtime.h>
#include <hip/hip_fp16.h>

#define DIM 256
#define MARGIN 2.25e-4f

typedef __bf16 bf8v __attribute__((ext_vector_type(8)));
typedef float f4v __attribute__((ext_vector_type(4)));
typedef unsigned int u32x4 __attribute__((ext_vector_type(4)));
typedef unsigned int u32x2 __attribute__((ext_vector_type(2)));

__device__ inline unsigned short f2bf(float x) {
    unsigned u = __float_as_uint(x);
    u += 0x7fffu + ((u >> 16) & 1u);   // RNE
    return (unsigned short)(u >> 16);
}

// ---------------- fused prep ----------------
__global__ __launch_bounds__(256) void k_prep(const float* __restrict__ z,
                                              const float* __restrict__ emb,
                                              float* __restrict__ zf,
                                              unsigned short* __restrict__ zb,
                                              unsigned short* __restrict__ eb,
                                              float* __restrict__ enorm,
                                              float* __restrict__ out_loss) {
    const int bx = blockIdx.x;
    if (bx < 2048) {
        __shared__ float tt[32][33];
        const int hw0 = (bx & 31) * 32;
        const int d0  = ((bx >> 5) & 7) * 32;
        const int b   = bx >> 8;
        const int tx = threadIdx.x & 31, ty = threadIdx.x >> 5;
#pragma unroll
        for (int i = 0; i < 4; i++) {
            const int d = d0 + ty + 8 * i;
            tt[ty + 8 * i][tx] = z[(b * 256 + d) * 1024 + hw0 + tx];
        }
        __syncthreads();
#pragma unroll
        for (int i = 0; i < 4; i++) {
            const int hw = hw0 + ty + 8 * i;
            const float v = tt[tx][ty + 8 * i];
            const size_t o = (size_t)(b * 1024 + hw) * DIM + d0 + tx;
            zf[o] = v;
            zb[o] = f2bf(v);
        }
    } else if (bx < 6144) {
        const int s = bx - 2048;
        const int wave = threadIdx.x >> 6, lane = threadIdx.x & 63;
        const int row = s * 4 + wave;
        const float4 v = *(const float4*)(emb + (size_t)row * DIM + lane * 4);
        ushort4 o;
        o.x = f2bf(v.x); o.y = f2bf(v.y); o.z = f2bf(v.z); o.w = f2bf(v.w);
        *(ushort4*)(eb + (size_t)row * DIM + lane * 4) = o;
        float ss = v.x * v.x + v.y * v.y + v.z * v.z + v.w * v.w;
#pragma unroll
        for (int m = 1; m < 64; m <<= 1) ss += __shfl_xor(ss, m, 64);
        if (lane == 0) enorm[row] = ss;
    } else {
        if (threadIdx.x == 0) out_loss[0] = 0.f;
    }
}

// ---------------- bf16 MFMA scoring: 64-row A in LDS (swizzled), B from L2 ----------------
// R14 mapping (col-major over by): chip-wide A reuse through L2/L3. (XCD-pinned swizzle
// regressed: FETCH 35->91 MB, R15.)
// Group g = by*16 + wc*4 + (m15>>2): codes by*256 + wc*64 + ct*16 + (m15>>2)*4 + l
__global__ __launch_bounds__(256, 4) void k_score(
        const unsigned short* __restrict__ zb, const unsigned short* __restrict__ eb,
        const float* __restrict__ enorm, unsigned short* __restrict__ pvalh) {
    __shared__ unsigned short As[64 * 256];   // 32 KB; reused as sm[64*16] in epilogue
    const int rx = blockIdx.x & 127;
    const int by = blockIdx.x >> 7;
    const int row0 = rx * 64;
    const int col0 = by * 256;
    const int t = threadIdx.x;
    const int lane = t & 63, wc = t >> 6;
    const int q = lane >> 4, m15 = lane & 15;

#pragma unroll
    for (int j = 0; j < 8; j++) {
        const int id = j * 256 + t;
        const int r = id >> 5, sl = id & 31;
        const int c = sl ^ (r & 15);
        __builtin_amdgcn_global_load_lds(
            (const __attribute__((address_space(1))) void*)(zb + (size_t)(row0 + r) * DIM + c * 8),
            (__attribute__((address_space(3))) void*)((char*)As + id * 16), 16, 0, 0);
    }
    __syncthreads();

    f4v acc[4][4];
#pragma unroll
    for (int rt = 0; rt < 4; rt++)
#pragma unroll
        for (int ct = 0; ct < 4; ct++) acc[rt][ct] = (f4v){0.f, 0.f, 0.f, 0.f};

    const unsigned short* brow = eb + (size_t)(col0 + wc * 64 + m15) * DIM + q * 8;

#pragma unroll
    for (int kk = 0; kk < 8; kk++) {
        bf8v af[4], bfv[4];
#pragma unroll
        for (int rt = 0; rt < 4; rt++) {
            const int r = rt * 16 + m15;
            const int slot = (kk * 4 + q) ^ m15;
            af[rt] = *(const bf8v*)&As[r * 256 + slot * 8];
        }
#pragma unroll
        for (int ct = 0; ct < 4; ct++)
            bfv[ct] = *(const bf8v*)(brow + (size_t)ct * 16 * DIM + kk * 32);
#pragma unroll
        for (int rt = 0; rt < 4; rt++)
#pragma unroll
            for (int ct = 0; ct < 4; ct++)
                acc[rt][ct] = __builtin_amdgcn_mfma_f32_16x16x32_bf16(af[rt], bfv[ct], acc[rt][ct], 0, 0, 0);
    }

    float en_l[4];
#pragma unroll
    for (int ct = 0; ct < 4; ct++) en_l[ct] = enorm[col0 + wc * 64 + ct * 16 + m15];
    float svr[4][4];
#pragma unroll
    for (int rt = 0; rt < 4; rt++) {
#pragma unroll
        for (int j = 0; j < 4; j++) {
            float s = fmaf(-2.f, acc[rt][0][j], en_l[0]);
#pragma unroll
            for (int ct = 1; ct < 4; ct++)
                s = fminf(s, fmaf(-2.f, acc[rt][ct][j], en_l[ct]));
            svr[rt][j] = s;
        }
#pragma unroll
        for (int m = 1; m <= 2; m <<= 1)
#pragma unroll
            for (int j = 0; j < 4; j++)
                svr[rt][j] = fminf(svr[rt][j], __shfl_xor(svr[rt][j], m, 64));
    }

    __syncthreads();
    unsigned short* sm = As;
    const int gsl = wc * 4 + (m15 >> 2);
    if ((m15 & 3) == 0) {
#pragma unroll
        for (int rt = 0; rt < 4; rt++) {
            const int rl = rt * 16 + q * 4;
#pragma unroll
            for (int j = 0; j < 4; j++)
                sm[(rl + j) * 16 + gsl] = __half_as_ushort(__float2half_rn(svr[rt][j]));
        }
    }
    __syncthreads();
    if (t < 128) {
        const u32x4 v = *(const u32x4*)&sm[t * 8];
        __builtin_nontemporal_store(v,
            (u32x4*)&pvalh[(size_t)(row0 + (t >> 1)) * 1024 + by * 16 + (t & 1) * 8]);
    }
}

// ---------------- select: block-per-row; 4 waves split 1024 groups (flag + rescore) ------------
// + fused epilogue: zq (NCHW) + loss atomicAdd + out_idx
__global__ __launch_bounds__(256) void k_select(
        const float* __restrict__ zf, const float* __restrict__ emb,
        const float* __restrict__ enorm, const unsigned short* __restrict__ pvalh,
        float* __restrict__ zq, float* __restrict__ out_idx,
        float* __restrict__ out_loss) {
    const int row = blockIdx.x;
    const int t = threadIdx.x;
    const int w = t >> 6, lane = t & 63;
    __shared__ float zs[256];
    __shared__ float wred[4], wmin[4], wloss[4];
    __shared__ int lcnt[4];
    __shared__ short list[4][256];
    __shared__ float fs[4];
    __shared__ int fi[4];
    __shared__ int winner;

    // z row into LDS + row norm partials (order-safe: enorm < half-ulp(zn))
    const float zv = zf[(size_t)row * DIM + t];
    zs[t] = zv;
    if (lane == 0) lcnt[w] = 0;
    float nrm = zv * zv;
#pragma unroll
    for (int m = 1; m < 64; m <<= 1) nrm += __shfl_xor(nrm, m, 64);
    if (lane == 0) wred[w] = nrm;

    // each thread scans 4 group-mins; wave w owns groups [w*256,(w+1)*256)
    const u32x2 u = __builtin_nontemporal_load((const u32x2*)(pvalh + (size_t)row * 1024 + t * 4));
    const __half* h = (const __half*)&u;
    float v[4];
#pragma unroll
    for (int k = 0; k < 4; k++) v[k] = __half2float(h[k]);
    float mn = fminf(fminf(v[0], v[1]), fminf(v[2], v[3]));
#pragma unroll
    for (int m = 1; m < 64; m <<= 1) mn = fminf(mn, __shfl_xor(mn, m, 64));
    if (lane == 0) wmin[w] = mn;
    __syncthreads();
    const float zn = wred[0] + wred[1] + wred[2] + wred[3];
    const float g = fminf(fminf(wmin[0], wmin[1]), fminf(wmin[2], wmin[3])) + MARGIN;

    // flag into wave-local list (wave-coherent LDS: no barrier needed before same-wave read)
#pragma unroll
    for (int k = 0; k < 4; k++) {
        if (v[k] <= g) {
            const int pos = atomicAdd(&lcnt[w], 1);
            if (pos < 256) list[w][pos] = (short)(t * 4 + k);
        }
    }
    const int n = min(lcnt[w], 256);

    // exact fp32 rescore of this wave's flagged groups: 4 codes parallel, 4 sub-rounds/group
    const int codei = lane >> 4, lane16 = lane & 15;
    float bv = 3.0e38f;
    int bi = 0x7fffffff;
    const float* zp = zs + lane16 * 16;
    for (int i = 0; i < n; i++) {
        const int gg = list[w][i];
        // code = (g>>4)*256 + ((g>>2)&3)*64 + ct*16 + (g&3)*4 + l,  ci = ct*4 + l
        const int cbase = ((gg >> 4) << 8) + (((gg >> 2) & 3) << 6) + ((gg & 3) << 2);
#pragma unroll
        for (int sub = 0; sub < 4; sub++) {
            const int ci = sub * 4 + codei;
            const int code = cbase + ((ci >> 2) << 4) + (ci & 3);
            const float* ep = emb + (size_t)code * DIM + lane16 * 16;
            float d = 0.f;
#pragma unroll
            for (int k = 0; k < 16; k += 4) {
                const float4 ev = *(const float4*)(ep + k);
                const float4 zv4 = *(const float4*)(zp + k);
                d = fmaf(zv4.x, ev.x, d);
                d = fmaf(zv4.y, ev.y, d);
                d = fmaf(zv4.z, ev.z, d);
                d = fmaf(zv4.w, ev.w, d);
            }
#pragma unroll
            for (int m = 1; m <= 8; m <<= 1) d += __shfl_xor(d, m, 64);
            if (lane16 == 0) {
                const float tt = zn + enorm[code];
                const float s = tt - 2.0f * d;   // exact fp32 semantics
                if (s < bv || (s == bv && code < bi)) { bv = s; bi = code; }
            }
        }
    }
    // wave-internal combine of the 4 writer lanes
#pragma unroll
    for (int m = 1; m < 64; m <<= 1) {
        const float ov = __shfl_xor(bv, m, 64);
        const int oi = __shfl_xor(bi, m, 64);
        if (ov < bv || (ov == bv && oi < bi)) { bv = ov; bi = oi; }
    }
    if (lane == 0) { fs[w] = bv; fi[w] = bi; }
    __syncthreads();
    if (t == 0) {
        float b = fs[0]; int c = fi[0];
#pragma unroll
        for (int k = 1; k < 4; k++)
            if (fs[k] < b || (fs[k] == b && fi[k] < c)) { b = fs[k]; c = fi[k]; }
        winner = c;
        out_idx[row] = (float)c;
    }
    __syncthreads();
    const int win = winner;

    // fused epilogue: coalesced emb read, NCHW scatter write, block loss
    const int b = row >> 10, hw = row & 1023;
    const float qv = emb[(size_t)win * DIM + t];
    const float dd = qv - zs[t];
    zq[((size_t)(b * 256 + t)) * 1024 + hw] = qv;
    float lsum = dd * dd;
#pragma unroll
    for (int m = 1; m < 64; m <<= 1) lsum += __shfl_xor(lsum, m, 64);
    if (lane == 0) wloss[w] = lsum;
    __syncthreads();
    if (t == 0) {
        const float total = wloss[0] + wloss[1] + wloss[2] + wloss[3];
        atomicAdd(out_loss, total * (1.25f / 2097152.0f));
    }
}

extern "C" void kernel_launch(void* const* d_in, const int* in_sizes, int n_in,
                              void* d_out, int out_size, void* d_ws, size_t ws_size,
                              hipStream_t stream) {
    const float* z   = (const float*)d_in[0];   // [8,256,32,32]
    const float* emb = (const float*)d_in[1];   // [16384,256]
    float* out = (float*)d_out;
    float* ws  = (float*)d_ws;

    // ws layout (float-slot offsets):
    float*          zf    = ws;                                   // 2,097,152  (8 MB)
    unsigned short* pvalh = (unsigned short*)(ws + 2097152);      // 8M halves  (16 MB)
    unsigned short* zb    = (unsigned short*)(ws + 6291456);      // 2M halves  (4 MB)
    unsigned short* eb    = (unsigned short*)(ws + 7340032);      // 4M halves  (8 MB)
    float*          enorm = ws + 9437184;                         // 16,384
    // total ≈ 37.8 MB

    float* zq       = out;                   // [8,256,32,32] NCHW
    float* out_loss = out + 2097152;         // scalar
    float* out_idx  = out + 2097153;         // [8192] as float32

    k_prep<<<dim3(6145), 256, 0, stream>>>(z, emb, zf, zb, eb, enorm, out_loss);
    k_score<<<dim3(8192), 256, 0, stream>>>(zb, eb, enorm, pvalh);
    k_select<<<dim3(8192), 256, 0, stream>>>(zf, emb, enorm, pvalh, zq, out_idx, out_loss);
}